// Round 1
// 512.869 us; speedup vs baseline: 1.2878x; 1.2878x over previous
//
#include <hip/hip_runtime.h>
#include <math.h>

#define Bz   8
#define Lz   8192
#define Hz   1024
#define Nz   64
#define BLz  (Bz * Lz)   // 65536

typedef __attribute__((ext_vector_type(8))) short bf16x8;
typedef __attribute__((ext_vector_type(4))) float f32x4;

__device__ inline unsigned int bfpack2(float a, float b) {
    // round-to-nearest-ish (round half up) bf16 pack of two floats
    unsigned int ua = __float_as_uint(a) + 0x8000u;
    unsigned int ub = __float_as_uint(b) + 0x8000u;
    return (ua >> 16) | (ub & 0xFFFF0000u);
}
__device__ inline unsigned short bf1(float a) {
    return (unsigned short)((__float_as_uint(a) + 0x8000u) >> 16);
}

// ---------------------------------------------------------------------------
// Prep: WinT[n][k] = bf16(Win[k][n])  (64 x 1024)
//       WoutT[h][n] = bf16(Wout[n][h]) (1024 x 64)
// ---------------------------------------------------------------------------
__global__ __launch_bounds__(256) void prep_kernel(
    const float* __restrict__ Win, const float* __restrict__ Wout,
    unsigned short* __restrict__ WinT, unsigned short* __restrict__ WoutT)
{
    int i = blockIdx.x * 256 + threadIdx.x;   // 0 .. 131071
    if (i < 65536) {
        int n = i >> 10, k = i & 1023;
        WinT[i] = bf1(Win[k * Nz + n]);
    } else {
        int j = i - 65536;
        int h = j >> 6, n = j & 63;
        WoutT[j] = bf1(Wout[n * Hz + h]);
    }
}

// ---------------------------------------------------------------------------
// GEMM1: u[bl,n] = sum_h input[bl,h] * Win[h,n]   (M=65536, N=64, K=1024)
// block 256 (4 waves). M-tile 128 (wave: 2 m-subtiles of 16), N=64 (4 n-tiles),
// K-chunk 64. mfma_f32_16x16x32_bf16.
// EPILOGUE CHANGE: writes u TRANSPOSED as ut[(b*Nz+n)*Lz + l] so the scan
// reads per-thread contiguous streams. reg walks rows(=l) -> one f32x4 store
// per (m,nt); lanes q=0..3 per nl chain into aligned 64B segments.
// ---------------------------------------------------------------------------
__global__ __launch_bounds__(256) void gemm_in_kernel(
    const float* __restrict__ inp, const unsigned short* __restrict__ WinT,
    float* __restrict__ u)
{
    __shared__ unsigned short sA[128][72];  // pad 72: 2-way bank alias only
    __shared__ unsigned short sB[64][72];

    const int t    = threadIdx.x;
    const int wid  = t >> 6;
    const int lane = t & 63;
    const int nl   = lane & 15;      // row-in-tile for A/B frags, col for C
    const int q    = lane >> 4;      // quad
    const size_t rowBase = (size_t)blockIdx.x * 128;

    f32x4 acc[2][4];
#pragma unroll
    for (int m = 0; m < 2; ++m)
#pragma unroll
        for (int nt = 0; nt < 4; ++nt) acc[m][nt] = (f32x4){0.f, 0.f, 0.f, 0.f};

    for (int kc = 0; kc < Hz; kc += 64) {
        __syncthreads();
        // stage A: 128 rows x 64 k fp32 -> bf16 LDS
#pragma unroll
        for (int j = 0; j < 4; ++j) {
            int f = j * 256 + t;           // chunk of 8 floats
            int r = f >> 3, c = f & 7;
            const float* p = inp + (rowBase + r) * Hz + kc + c * 8;
            float4 v0 = *reinterpret_cast<const float4*>(p);
            float4 v1 = *reinterpret_cast<const float4*>(p + 4);
            uint4 d;
            d.x = bfpack2(v0.x, v0.y);
            d.y = bfpack2(v0.z, v0.w);
            d.z = bfpack2(v1.x, v1.y);
            d.w = bfpack2(v1.z, v1.w);
            *reinterpret_cast<uint4*>(&sA[r][c * 8]) = d;
        }
        // stage B^T: 64 n-rows x 64 k bf16 from WinT
#pragma unroll
        for (int j = 0; j < 2; ++j) {
            int f = j * 256 + t;
            int r = f >> 3, c = f & 7;
            uint4 w = *reinterpret_cast<const uint4*>(WinT + (size_t)r * Hz + kc + c * 8);
            *reinterpret_cast<uint4*>(&sB[r][c * 8]) = w;
        }
        __syncthreads();

#pragma unroll
        for (int ks = 0; ks < 2; ++ks) {
            bf16x8 a0 = *reinterpret_cast<bf16x8*>(&sA[wid * 32 + nl][ks * 32 + q * 8]);
            bf16x8 a1 = *reinterpret_cast<bf16x8*>(&sA[wid * 32 + 16 + nl][ks * 32 + q * 8]);
#pragma unroll
            for (int nt = 0; nt < 4; ++nt) {
                bf16x8 b = *reinterpret_cast<bf16x8*>(&sB[nt * 16 + nl][ks * 32 + q * 8]);
                acc[0][nt] = __builtin_amdgcn_mfma_f32_16x16x32_bf16(a0, b, acc[0][nt], 0, 0, 0);
                acc[1][nt] = __builtin_amdgcn_mfma_f32_16x16x32_bf16(a1, b, acc[1][nt], 0, 0, 0);
            }
        }
    }

    // epilogue: C/D layout col = lane&15, row = quad*4 + reg.
    // Transposed write: ut[(b*Nz+n)*Lz + l]. Blocks of 128 rows never
    // straddle a batch boundary (8192 % 128 == 0).
    const int bI = (int)(rowBase >> 13);                    // batch index
    const int l0 = ((int)rowBase & (Lz - 1)) + wid * 32 + q * 4;
#pragma unroll
    for (int m = 0; m < 2; ++m)
#pragma unroll
        for (int nt = 0; nt < 4; ++nt) {
            const int nn = nt * 16 + nl;
            *reinterpret_cast<f32x4*>(
                u + (((size_t)(bI * Nz + nn)) << 13) + (l0 + m * 16)) = acc[m][nt];
        }
}

// ---------------------------------------------------------------------------
// Scan: x[t] = a*x[t-1] + u[t] (complex a). conv written as bf16.
// u is TRANSPOSED: ut[(b*Nz+n)*Lz + l] -> thread n streams its own row with
// float4 loads. 64 steps/group, 2-group ping-pong register prefetch
// (load-use distance ~2 groups ~ 1024 cyc, covers HBM-miss latency).
// All buffer indices compile-time (full unroll) -> stays in VGPRs.
// ---------------------------------------------------------------------------
#define CHUNK 512
#define WARM  192
#define GSTEP 64

#define SSTEP(UV, IDX)                                              \
    {                                                               \
        float nr_ = fmaf(ar, xr, fmaf(-ai, xi, (UV)));              \
        float ni_ = fmaf(ar, xi, ai * xr);                          \
        xr = nr_; xi = ni_;                                         \
        if (emit_) cp_[(size_t)(IDX) * Nz] = bf1(xr);               \
    }

#define DO_GROUP(BUF, G)                                            \
    {                                                               \
        const int g_ = (G);                                         \
        const bool emit_ = (g_ >= emitG);                           \
        const bool pf_ = (g_ + 2 < nG);                             \
        unsigned short* cp_ = cb + (size_t)(g_ * GSTEP) * Nz;       \
        const float4* np_ = up + (g_ + 2) * (GSTEP / 4);            \
        _Pragma("unroll")                                           \
        for (int k = 0; k < 16; ++k) {                              \
            float4 v_ = BUF[k];                                     \
            if (pf_) BUF[k] = np_[k];                               \
            SSTEP(v_.x, k * 4 + 0)                                  \
            SSTEP(v_.y, k * 4 + 1)                                  \
            SSTEP(v_.z, k * 4 + 2)                                  \
            SSTEP(v_.w, k * 4 + 3)                                  \
        }                                                           \
    }

__global__ __launch_bounds__(64) void scan_kernel(
    const float* __restrict__ ut, const float* __restrict__ init,
    const float* __restrict__ freq, const float* __restrict__ dec,
    unsigned short* __restrict__ convb, float* __restrict__ fs, int fs_mode)
{
    const int n = threadIdx.x;
    const int b = blockIdx.x;
    const int c = blockIdx.y;

    const float mag = expf(-expf(dec[n]));
    const float fr  = freq[n];
    const float ar  = mag * cosf(fr);
    const float ai  = mag * sinf(fr);

    const int s0    = (c == 0) ? 0 : (c * CHUNK - WARM);                 // mult of 16
    const int nG    = (c == 0) ? (CHUNK / GSTEP) : ((CHUNK + WARM) / GSTEP); // 8 or 11
    const int emitG = (c == 0) ? 0 : (WARM / GSTEP);                     // 0 or 3

    const float4* up = reinterpret_cast<const float4*>(
                           ut + (((size_t)(b * Nz + n)) << 13)) + (s0 >> 2);
    unsigned short* cb = convb + ((size_t)b * Lz + s0) * Nz + n;

    float xr = (c == 0) ? init[b * Nz + n] : 0.f;
    float xi = 0.f;

    float4 bufA[16], bufB[16];
#pragma unroll
    for (int k = 0; k < 16; ++k) bufA[k] = up[k];
#pragma unroll
    for (int k = 0; k < 16; ++k) bufB[k] = up[16 + k];

    const int nG2 = nG & ~1;
    for (int g = 0; g < nG2; g += 2) {
        DO_GROUP(bufA, g)
        DO_GROUP(bufB, g + 1)
    }
    if (nG & 1) { DO_GROUP(bufA, nG - 1) }

    if (c == (Lz / CHUNK) - 1 && fs_mode) {
        if (fs_mode == 2) {
            fs[(b * Nz + n) * 2 + 0] = xr;
            fs[(b * Nz + n) * 2 + 1] = xi;
        } else {
            fs[b * Nz + n] = xr;
        }
    }
}

// ---------------------------------------------------------------------------
// GEMM2: out[bl,h] = sum_n conv[bl,n] * Wout[n,h]  (M=65536, N=1024, K=64)
// block 512 (8 waves): rows = 128 (wave: 16 rows), h-slice = 256 (16 h-tiles).
// WoutT slice in LDS; A-frags direct from global (contiguous bf16 rows).
// Store each 16x16 tile immediately (acc stays tiny -> high occupancy).
// ---------------------------------------------------------------------------
__global__ __launch_bounds__(512) void gemm_out_kernel(
    const unsigned short* __restrict__ convb,
    const unsigned short* __restrict__ WoutT,
    float* __restrict__ out)
{
    __shared__ unsigned short sW[256][72];   // 36.9 KB

    const int t    = threadIdx.x;
    const int wid  = t >> 6;
    const int lane = t & 63;
    const int nl   = lane & 15;
    const int q    = lane >> 4;
    const int hBase = blockIdx.x * 256;
    const size_t rowBase = (size_t)blockIdx.y * 128 + wid * 16;

    // stage WoutT slice: 256 h-rows x 64 n
#pragma unroll
    for (int j = 0; j < 4; ++j) {
        int f = j * 512 + t;
        int r = f >> 3, c = f & 7;
        uint4 v = *reinterpret_cast<const uint4*>(WoutT + (size_t)(hBase + r) * Nz + c * 8);
        *reinterpret_cast<uint4*>(&sW[r][c * 8]) = v;
    }
    __syncthreads();

    // A fragments: conv rows (bf16, 64 per row): k = ks*32 + q*8 + j
    const unsigned short* ap = convb + (rowBase + nl) * Nz;
    bf16x8 a0 = *reinterpret_cast<const bf16x8*>(ap + q * 8);
    bf16x8 a1 = *reinterpret_cast<const bf16x8*>(ap + 32 + q * 8);

    const f32x4 zero = (f32x4){0.f, 0.f, 0.f, 0.f};
#pragma unroll
    for (int ht = 0; ht < 16; ++ht) {
        bf16x8 b0 = *reinterpret_cast<bf16x8*>(&sW[ht * 16 + nl][q * 8]);
        bf16x8 b1 = *reinterpret_cast<bf16x8*>(&sW[ht * 16 + nl][32 + q * 8]);
        f32x4 acc = __builtin_amdgcn_mfma_f32_16x16x32_bf16(a0, b0, zero, 0, 0, 0);
        acc = __builtin_amdgcn_mfma_f32_16x16x32_bf16(a1, b1, acc, 0, 0, 0);
#pragma unroll
        for (int reg = 0; reg < 4; ++reg)
            out[(rowBase + q * 4 + reg) * Hz + hBase + ht * 16 + nl] = acc[reg];
    }
}

// ---------------------------------------------------------------------------
extern "C" void kernel_launch(void* const* d_in, const int* in_sizes, int n_in,
                              void* d_out, int out_size, void* d_ws, size_t ws_size,
                              hipStream_t stream)
{
    const float* inp  = (const float*)d_in[0];   // (B, L, H)
    const float* init = (const float*)d_in[1];   // (B, N)
    const float* Win  = (const float*)d_in[2];   // (H, N)
    const float* Wout = (const float*)d_in[3];   // (N, H)
    const float* freq = (const float*)d_in[4];   // (N,)
    const float* dec  = (const float*)d_in[5];   // (N,)
    float* out = (float*)d_out;

    char* ws = (char*)d_ws;
    float*          u     = (float*)ws;                               // 16.78 MB (ut, transposed)
    unsigned short* convb = (unsigned short*)(ws + (size_t)BLz * Nz * 4);       // 8.39 MB
    unsigned short* WinT  = (unsigned short*)(ws + (size_t)BLz * Nz * 6);       // 128 KB
    unsigned short* WoutT = WinT + (size_t)Nz * Hz;                             // 128 KB

    const int extra   = out_size - BLz * Hz;
    const int fs_mode = (extra >= 2 * Bz * Nz) ? 2 : (extra >= Bz * Nz ? 1 : 0);
    float* fs = out + (size_t)BLz * Hz;

    hipLaunchKernelGGL(prep_kernel, dim3(512), dim3(256), 0, stream,
                       Win, Wout, WinT, WoutT);
    hipLaunchKernelGGL(gemm_in_kernel, dim3(BLz / 128), dim3(256), 0, stream,
                       inp, WinT, u);
    hipLaunchKernelGGL(scan_kernel, dim3(Bz, Lz / CHUNK), dim3(64), 0, stream,
                       u, init, freq, dec, convb, fs, fs_mode);
    hipLaunchKernelGGL(gemm_out_kernel, dim3(Hz / 256, BLz / 128), dim3(512), 0, stream,
                       convb, WoutT, out);
}